// Round 6
// baseline (976.019 us; speedup 1.0000x reference)
//
#include <hip/hip_runtime.h>
#include <hip/hip_bf16.h>

// RCNN: bidirectional simple-RNN + conv1x1 + global max pool + dense sigmoid
// B=256 T=512 V=50000 E=128 H=256 C=128
//
// "unit" = 512 B = 64 lanes x 8 B (4 bf16). For batch-tile b0, time t, unit u
// lives in x-row (b0+u)*T+t. Short s = 64*q + 4*l15 + i  <->  (col 16u+4q+i,
// batch b0+l15).  x row layout (640 shorts): [0,256) h_f/xw_f units u=0..15,
// [256,384) e_cur units u=0..7 (q-half split), [384,640) h_b/xw_b units.
//
// rnn: 16 blocks x 8 waves. Waves 0-3 = fwd chain, waves 4-7 = bwd chain of
// the same 16-batch tile -> each SIMD hosts one wave of EACH independent
// chain (2 waves/SIMD latency overlap, R3) while each wave does 64 cols with
// C-operand seeded from xw + T-unroll x2 + prefetch-4 (R4/R5 body).
// h overwrites xw in place at slot t. Barrier drains LDS only (lgkmcnt).

#define B_ 256
#define T_ 512
#define E_ 128
#define H_ 256
#define C_ 128

typedef __attribute__((ext_vector_type(8))) short short8;
typedef __attribute__((ext_vector_type(4))) float float4v;
typedef __attribute__((ext_vector_type(2))) unsigned int uint2v;

__device__ inline unsigned short f2bf(float f) {
  unsigned u = __float_as_uint(f);
  u += 0x7fffu + ((u >> 16) & 1u);  // RNE
  return (unsigned short)(u >> 16);
}
__device__ inline unsigned pkbf(float a, float b) {
  __hip_bfloat162 h2 = __float22bfloat162_rn(float2{a, b});
  union { __hip_bfloat162 h; unsigned u; } cv;
  cv.h = h2;
  return cv.u;
}
__device__ inline float lo16f(unsigned u) { return __uint_as_float(u << 16); }
__device__ inline float hi16f(unsigned u) { return __uint_as_float(u & 0xffff0000u); }
__device__ inline float fast_tanh(float x) {
  float e = __expf(2.f * x);                 // inf ok -> 1
  float r = __builtin_amdgcn_rcpf(e + 1.f);
  return __builtin_fmaf(-2.f, r, 1.f);
}
__device__ inline unsigned enc_f(float f) {
  unsigned u = __float_as_uint(f);
  return (u & 0x80000000u) ? ~u : (u | 0x80000000u);
}
__device__ inline float dec_f(unsigned key) {
  unsigned bits = (key & 0x80000000u) ? (key ^ 0x80000000u) : ~key;
  return __uint_as_float(bits);
}
__device__ inline void sync_lds() {
  asm volatile("s_waitcnt lgkmcnt(0)\n\ts_barrier" ::: "memory");
}

// ---------------------------------------------------------------------------
// prep: transpose + bf16-cast weights. WfT/WbT:[256][128] WcT:[128][640]
// UfT/UbT:[256][256]  (all [n][k])
// ---------------------------------------------------------------------------
__global__ __launch_bounds__(256) void prep_kernel(
    const float* __restrict__ Wf, const float* __restrict__ Wb,
    const float* __restrict__ Wc, const float* __restrict__ Uf,
    const float* __restrict__ Ub,
    unsigned short* __restrict__ WfT, unsigned short* __restrict__ WbT,
    unsigned short* __restrict__ WcT, unsigned short* __restrict__ UfT,
    unsigned short* __restrict__ UbT) {
  int gid = blockIdx.x * 256 + threadIdx.x;
  int stride = gridDim.x * 256;
  for (int i = gid; i < 256 * 128; i += stride) {
    int n = i >> 7, k = i & 127;
    WfT[i] = f2bf(Wf[k * 256 + n]);
    WbT[i] = f2bf(Wb[k * 256 + n]);
  }
  for (int i = gid; i < 128 * 640; i += stride) {
    int n = i / 640, k = i - n * 640;
    WcT[i] = f2bf(Wc[k * 128 + n]);
  }
  for (int i = gid; i < 256 * 256; i += stride) {
    int n = i >> 8, k = i & 255;
    UfT[i] = f2bf(Uf[k * 256 + n]);
    UbT[i] = f2bf(Ub[k * 256 + n]);
  }
}

// ---------------------------------------------------------------------------
// embxw: dirs 0/1: xw^T = W^T . e^T + b, packed units into x.
//        dir 2: plain gather of e_cur into q-half-split units [256,384).
// grid (128 tquads, 16 btiles, 3), 256 thr.
// ---------------------------------------------------------------------------
__global__ __launch_bounds__(256) void embxw_kernel(
    const int* __restrict__ idxL, const int* __restrict__ idxR,
    const int* __restrict__ idxC, const float* __restrict__ emb,
    const unsigned short* __restrict__ WfT, const unsigned short* __restrict__ WbT,
    const float* __restrict__ bfv, const float* __restrict__ bbv,
    unsigned short* __restrict__ x) {
  const int dir = blockIdx.z;
  const int t0 = blockIdx.x * 4;
  const int b0 = blockIdx.y * 16;
  const int tid = threadIdx.x;
  const int w = tid >> 6, lane = tid & 63, q = lane >> 4, l15 = lane & 15;

  if (dir == 2) {  // e_cur gather
    const int t = t0 + w;
    const int er = idxC[(b0 + l15) * T_ + t];
    const float* ep = emb + (size_t)er * E_;
#pragma unroll
    for (int u = 0; u < 8; ++u) {
      float4v a = *(const float4v*)(ep + 16 * u + 4 * q);
      uint2v pk = {pkbf(a[0], a[1]), pkbf(a[2], a[3])};
      int row = b0 + u + 8 * (q >> 1);
      *(uint2v*)(x + ((size_t)row * T_ + t) * 640 + 256 + 64 * (q & 1) +
                 4 * l15) = pk;
    }
    return;
  }

  const int* __restrict__ idx = dir ? idxR : idxL;
  const unsigned short* __restrict__ WT = dir ? WbT : WfT;
  const float* __restrict__ bias = dir ? bbv : bfv;

  short8 wfr[4][4];
#pragma unroll
  for (int mt = 0; mt < 4; ++mt)
#pragma unroll
    for (int kt = 0; kt < 4; ++kt)
      wfr[mt][kt] = *(const short8*)(WT + (64 * w + 16 * mt + l15) * 128 +
                                     kt * 32 + q * 8);
  float4v bv[4];
#pragma unroll
  for (int mt = 0; mt < 4; ++mt)
    bv[mt] = *(const float4v*)(bias + 64 * w + 16 * mt + 4 * q);

#pragma unroll 1
  for (int j = 0; j < 4; ++j) {
    const int t = t0 + j;
    const int er = idx[(b0 + l15) * T_ + t];
    const float* ep = emb + (size_t)er * E_;
    short8 efr[4];
#pragma unroll
    for (int kt = 0; kt < 4; ++kt) {
      const float* p8 = ep + kt * 32 + q * 8;
      float4v a0 = *(const float4v*)p8;
      float4v a1 = *(const float4v*)(p8 + 4);
      union { unsigned u[4]; short8 s; } cv;
      cv.u[0] = pkbf(a0[0], a0[1]);
      cv.u[1] = pkbf(a0[2], a0[3]);
      cv.u[2] = pkbf(a1[0], a1[1]);
      cv.u[3] = pkbf(a1[2], a1[3]);
      efr[kt] = cv.s;
    }
    float4v acc[4];
#pragma unroll
    for (int mt = 0; mt < 4; ++mt) acc[mt] = (float4v){0.f, 0.f, 0.f, 0.f};
#pragma unroll
    for (int kt = 0; kt < 4; ++kt)
#pragma unroll
      for (int mt = 0; mt < 4; ++mt)
        acc[mt] = __builtin_amdgcn_mfma_f32_16x16x32_bf16(wfr[mt][kt], efr[kt],
                                                          acc[mt], 0, 0, 0);
#pragma unroll
    for (int mt = 0; mt < 4; ++mt) {
      float4v v = acc[mt] + bv[mt];
      uint2v pk = {pkbf(v[0], v[1]), pkbf(v[2], v[3])};
      *(uint2v*)(x + ((size_t)(b0 + 4 * w + mt) * T_ + t) * 640 + dir * 384 +
                 lane * 4) = pk;
    }
  }
}

// ---------------------------------------------------------------------------
// rnn: h_t = tanh(U^T h^T ; C-seed = xw_t). Dual-chain: waves 0-3 fwd,
// waves 4-7 bwd, 64 cols each. 16 blocks x 512 thr. Unroll x2, prefetch 4.
// ---------------------------------------------------------------------------
__global__ __launch_bounds__(512, 2) void rnn_kernel(
    unsigned short* x, const unsigned short* __restrict__ UfT,
    const unsigned short* __restrict__ UbT) {
  const int b0 = blockIdx.x * 16;
  const int tid = threadIdx.x;
  const int wave = tid >> 6, lane = tid & 63, q = lane >> 4, l15 = lane & 15;
  const int chain = wave >> 2;  // 0 = fwd, 1 = bwd
  const int wv = wave & 3;      // wave within chain, 64 cols each
  const unsigned short* __restrict__ UT = chain ? UbT : UfT;
  const int xoff = chain ? 384 : 0;
  const int tstep = chain ? -1 : 1;
  const int t0 = chain ? (T_ - 1) : 0;
  const ptrdiff_t dstep = (ptrdiff_t)tstep * 640;  // shorts per t-step

  // stride 280 shorts: b128 bank-start 4*(3*l15+q)%32 -> 2-way (free)
  __shared__ __attribute__((aligned(16))) unsigned short hbuf[2][2][16][280];
  unsigned short* hb0 = &hbuf[chain][0][0][0];
  unsigned short* hb1 = &hbuf[chain][1][0][0];

  for (int i = tid; i < 16 * 280; i += 512) {
    hbuf[0][0][0][i] = 0;
    hbuf[1][0][0][i] = 0;
  }

  // U^T A-fragments for this wave's 64 output cols (4 m-tiles x 8 k-tiles)
  short8 ufr[4][8];
#pragma unroll
  for (int mt = 0; mt < 4; ++mt)
#pragma unroll
    for (int kt = 0; kt < 8; ++kt)
      ufr[mt][kt] = *(const short8*)(UT + (64 * wv + 16 * mt + l15) * H_ +
                                     kt * 32 + q * 8);

  // per-lane unit pointers: units u = 4*wv + mt
  unsigned short* ptrS[4];        // store slot (step t of current pair)
  const unsigned short* ptrL[4];  // load slot (t + 4*tstep)
  uint2v curA[4], curB[4], infA[4], infB[4];
#pragma unroll
  for (int mt = 0; mt < 4; ++mt) {
    unsigned short* base =
        x + (size_t)(b0 + 4 * wv + mt) * T_ * 640 + xoff + lane * 4;
    unsigned short* bt = base + (ptrdiff_t)t0 * 640;
    curA[mt] = *(const uint2v*)(bt);
    curB[mt] = *(const uint2v*)(bt + dstep);
    infA[mt] = *(const uint2v*)(bt + 2 * dstep);
    infB[mt] = *(const uint2v*)(bt + 3 * dstep);
    ptrS[mt] = bt;
    ptrL[mt] = bt + 4 * dstep;
  }

  const unsigned lrd = l15 * 280;            // LDS read row base
  const unsigned lwr = l15 * 280 + 64 * wv;  // LDS write base (+16mt+4q)

  __syncthreads();

#pragma unroll 1
  for (int p = 0; p < 256; ++p) {
    // prefetch pair p+2's xw (steps 2p+4, 2p+5)
    uint2v ldA[4], ldB[4];
    if (p < 254) {
#pragma unroll
      for (int mt = 0; mt < 4; ++mt) {
        ldA[mt] = *(const uint2v*)(ptrL[mt]);
        ldB[mt] = *(const uint2v*)(ptrL[mt] + dstep);
      }
    } else {
#pragma unroll
      for (int mt = 0; mt < 4; ++mt) { ldA[mt] = infA[mt]; ldB[mt] = infB[mt]; }
    }
#pragma unroll
    for (int mt = 0; mt < 4; ++mt) ptrL[mt] += 2 * dstep;

    // ---- STEP A: read hb0, write hb1 ----
    {
      short8 afr[8];
#pragma unroll
      for (int kt = 0; kt < 8; ++kt)
        afr[kt] = *(const short8*)(hb0 + lrd + kt * 32 + q * 8);
      float4v acc[4];
#pragma unroll
      for (int mt = 0; mt < 4; ++mt)
        acc[mt] = (float4v){lo16f(curA[mt].x), hi16f(curA[mt].x),
                            lo16f(curA[mt].y), hi16f(curA[mt].y)};
#pragma unroll
      for (int kt = 0; kt < 8; ++kt)
#pragma unroll
        for (int mt = 0; mt < 4; ++mt)
          acc[mt] = __builtin_amdgcn_mfma_f32_16x16x32_bf16(
              ufr[mt][kt], afr[kt], acc[mt], 0, 0, 0);
#pragma unroll
      for (int mt = 0; mt < 4; ++mt) {
        uint2v hv = {pkbf(fast_tanh(acc[mt][0]), fast_tanh(acc[mt][1])),
                     pkbf(fast_tanh(acc[mt][2]), fast_tanh(acc[mt][3]))};
        *(uint2v*)(hb1 + lwr + 16 * mt + 4 * q) = hv;
        *(uint2v*)ptrS[mt] = hv;
      }
    }
    sync_lds();

    // ---- STEP B: read hb1, write hb0 ----
    {
      short8 afr[8];
#pragma unroll
      for (int kt = 0; kt < 8; ++kt)
        afr[kt] = *(const short8*)(hb1 + lrd + kt * 32 + q * 8);
      float4v acc[4];
#pragma unroll
      for (int mt = 0; mt < 4; ++mt)
        acc[mt] = (float4v){lo16f(curB[mt].x), hi16f(curB[mt].x),
                            lo16f(curB[mt].y), hi16f(curB[mt].y)};
#pragma unroll
      for (int kt = 0; kt < 8; ++kt)
#pragma unroll
        for (int mt = 0; mt < 4; ++mt)
          acc[mt] = __builtin_amdgcn_mfma_f32_16x16x32_bf16(
              ufr[mt][kt], afr[kt], acc[mt], 0, 0, 0);
#pragma unroll
      for (int mt = 0; mt < 4; ++mt) {
        uint2v hv = {pkbf(fast_tanh(acc[mt][0]), fast_tanh(acc[mt][1])),
                     pkbf(fast_tanh(acc[mt][2]), fast_tanh(acc[mt][3]))};
        *(uint2v*)(hb0 + lwr + 16 * mt + 4 * q) = hv;
        *(uint2v*)(ptrS[mt] + dstep) = hv;
      }
    }
#pragma unroll
    for (int mt = 0; mt < 4; ++mt) {
      ptrS[mt] += 2 * dstep;
      curA[mt] = infA[mt];
      curB[mt] = infB[mt];
      infA[mt] = ldA[mt];
      infB[mt] = ldB[mt];
    }
    sync_lds();
  }
}

// ---------------------------------------------------------------------------
// convpool: out = max_t tanh(x_row @ Wc + bc). grid (16 btiles x 32 tchunks),
// 256 thr (4 waves x 32 c-cols). x tile staged through LDS per t (dbuf).
// ---------------------------------------------------------------------------
__global__ __launch_bounds__(256, 2) void convpool_kernel(
    const unsigned short* __restrict__ x, const unsigned short* __restrict__ WcT,
    const float* __restrict__ bc, unsigned int* __restrict__ pooled) {
  const int b0 = (blockIdx.x & 15) * 16;
  const int t0 = (blockIdx.x >> 4) * 16;
  const int tid = threadIdx.x;
  const int w = tid >> 6, lane = tid & 63, q = lane >> 4, l15 = lane & 15;

  __shared__ __attribute__((aligned(16))) unsigned short tile[2][16][648];

  short8 wfr[2][20];
#pragma unroll
  for (int ct = 0; ct < 2; ++ct)
#pragma unroll
    for (int kt = 0; kt < 20; ++kt)
      wfr[ct][kt] = *(const short8*)(WcT +
                                     (size_t)(32 * w + 16 * ct + l15) * 640 +
                                     kt * 32 + q * 8);
  float4v bv[2];
#pragma unroll
  for (int ct = 0; ct < 2; ++ct)
    bv[ct] = *(const float4v*)(bc + 32 * w + 16 * ct + 4 * q);

  float4v mx[2];
  mx[0] = (float4v){-1e30f, -1e30f, -1e30f, -1e30f};
  mx[1] = mx[0];

  const int srow = tid >> 4, ssub = tid & 15;
  {
    const unsigned short* src = x + ((size_t)(b0 + srow) * T_ + t0) * 640;
#pragma unroll
    for (int j = 0; j < 5; ++j)
      *(short8*)&tile[0][srow][ssub * 8 + j * 128] =
          *(const short8*)(src + ssub * 8 + j * 128);
  }
  __syncthreads();

#pragma unroll 1
  for (int j = 0; j < 16; ++j) {
    const int t = t0 + j;
    const int buf = j & 1;
    if (j < 15) {
      const unsigned short* src = x + ((size_t)(b0 + srow) * T_ + t + 1) * 640;
#pragma unroll
      for (int jj = 0; jj < 5; ++jj)
        *(short8*)&tile[buf ^ 1][srow][ssub * 8 + jj * 128] =
            *(const short8*)(src + ssub * 8 + jj * 128);
    }
    float4v acc[2];
    acc[0] = (float4v){0.f, 0.f, 0.f, 0.f};
    acc[1] = (float4v){0.f, 0.f, 0.f, 0.f};
#pragma unroll
    for (int kt = 0; kt < 20; ++kt) {
      int row, so1, so2;
      if (kt < 8) {
        row = 2 * kt + (q >> 1);
        so1 = 64 * (2 * (q & 1)) + 4 * l15;
        so2 = so1 + 64;
      } else if (kt < 12) {
        row = 2 * (kt - 8) + (q >> 1) + 8 * (q & 1);
        so1 = 256 + 4 * l15;
        so2 = 320 + 4 * l15;
      } else {
        row = 2 * (kt - 12) + (q >> 1);
        so1 = 384 + 64 * (2 * (q & 1)) + 4 * l15;
        so2 = so1 + 64;
      }
      union { unsigned u[4]; short8 s; } cv;
      uint2v c1 = *(const uint2v*)&tile[buf][row][so1];
      uint2v c2 = *(const uint2v*)&tile[buf][row][so2];
      cv.u[0] = c1.x; cv.u[1] = c1.y; cv.u[2] = c2.x; cv.u[3] = c2.y;
      acc[0] = __builtin_amdgcn_mfma_f32_16x16x32_bf16(wfr[0][kt], cv.s,
                                                       acc[0], 0, 0, 0);
      acc[1] = __builtin_amdgcn_mfma_f32_16x16x32_bf16(wfr[1][kt], cv.s,
                                                       acc[1], 0, 0, 0);
    }
#pragma unroll
    for (int ct = 0; ct < 2; ++ct)
#pragma unroll
      for (int i = 0; i < 4; ++i)
        mx[ct][i] = fmaxf(mx[ct][i], fast_tanh(acc[ct][i] + bv[ct][i]));
    __syncthreads();
  }
#pragma unroll
  for (int ct = 0; ct < 2; ++ct)
#pragma unroll
    for (int i = 0; i < 4; ++i)
      atomicMax(pooled + (b0 + l15) * C_ + 32 * w + 16 * ct + 4 * q + i,
                enc_f(mx[ct][i]));
}

// ---------------------------------------------------------------------------
// dense: out = sigmoid(pooled @ Wd + bd)  [256,128]@[128,2]
// ---------------------------------------------------------------------------
__global__ __launch_bounds__(256) void dense_kernel(
    const unsigned int* __restrict__ pooled, const float* __restrict__ Wd,
    const float* __restrict__ bd, float* __restrict__ out) {
  int b = threadIdx.x;
  float s0 = bd[0], s1 = bd[1];
#pragma unroll 4
  for (int c = 0; c < C_; ++c) {
    float f = dec_f(pooled[b * C_ + c]);
    s0 += f * Wd[c * 2 + 0];
    s1 += f * Wd[c * 2 + 1];
  }
  out[b * 2 + 0] = 1.f / (1.f + __expf(-s0));
  out[b * 2 + 1] = 1.f / (1.f + __expf(-s1));
}

// ---------------------------------------------------------------------------
extern "C" void kernel_launch(void* const* d_in, const int* in_sizes, int n_in,
                              void* d_out, int out_size, void* d_ws, size_t ws_size,
                              hipStream_t stream) {
  const int* idxC = (const int*)d_in[0];
  const int* idxL = (const int*)d_in[1];
  const int* idxR = (const int*)d_in[2];
  const float* emb = (const float*)d_in[3];
  const float* Wf = (const float*)d_in[4];
  const float* Uf = (const float*)d_in[5];
  const float* bf_ = (const float*)d_in[6];
  const float* Wb = (const float*)d_in[7];
  const float* Ub = (const float*)d_in[8];
  const float* bb_ = (const float*)d_in[9];
  const float* Wc = (const float*)d_in[10];
  const float* bc = (const float*)d_in[11];
  const float* Wd = (const float*)d_in[12];
  const float* bd = (const float*)d_in[13];

  char* ws = (char*)d_ws;
  unsigned short* x = (unsigned short*)ws;                          // 167,772,160 B
  unsigned int* pooled = (unsigned int*)(ws + 167772160);           // 131,072 B
  unsigned short* WfT = (unsigned short*)(ws + 167772160 + 131072);
  unsigned short* WbT = WfT + 256 * 128;
  unsigned short* WcT = WbT + 256 * 128;
  unsigned short* UfT = WcT + 128 * 640;
  unsigned short* UbT = UfT + 256 * 256;

  hipMemsetAsync(pooled, 0, B_ * C_ * sizeof(unsigned int), stream);
  prep_kernel<<<64, 256, 0, stream>>>(Wf, Wb, Wc, Uf, Ub, WfT, WbT, WcT, UfT, UbT);
  embxw_kernel<<<dim3(128, 16, 3), 256, 0, stream>>>(idxL, idxR, idxC, emb,
                                                     WfT, WbT, bf_, bb_, x);
  rnn_kernel<<<16, 512, 0, stream>>>(x, UfT, UbT);
  convpool_kernel<<<512, 256, 0, stream>>>(x, WcT, bc, pooled);
  dense_kernel<<<1, 256, 0, stream>>>(pooled, Wd, bd, (float*)d_out);
}

// Round 7
// 629.830 us; speedup vs baseline: 1.5497x; 1.5497x over previous
//
#include <hip/hip_runtime.h>
#include <hip/hip_bf16.h>

// RCNN: bidirectional simple-RNN + conv1x1 + global max pool + dense sigmoid
// B=256 T=512 V=50000 E=128 H=256 C=128
//
// "unit" = 512 B = 64 lanes x 8 B (4 bf16). For batch-tile b0, time t, unit u
// lives in x-row (b0+u)*T+t. Short s = 64*q + 4*l15 + i  <->  (col 16u+4q+i,
// batch b0+l15).  x row layout (640 shorts): [0,256) h_f/xw_f units u=0..15,
// [256,384) e_cur units u=0..7 (q-half split), [384,640) h_b/xw_b units.
//
// rnn: R4 configuration (measured 375 us = DS-volume floor of this
// decomposition): 32 blocks (16 btiles x 2 dirs) x 8 waves x 32 cols,
// 2 same-chain waves/SIMD, MFMA C-operand seeded with xw, T-unroll x2,
// xw prefetch distance 4, h in-place over xw at slot t, LDS-only barrier.

#define B_ 256
#define T_ 512
#define E_ 128
#define H_ 256
#define C_ 128

typedef __attribute__((ext_vector_type(8))) short short8;
typedef __attribute__((ext_vector_type(4))) float float4v;
typedef __attribute__((ext_vector_type(2))) unsigned int uint2v;

__device__ inline unsigned short f2bf(float f) {
  unsigned u = __float_as_uint(f);
  u += 0x7fffu + ((u >> 16) & 1u);  // RNE
  return (unsigned short)(u >> 16);
}
__device__ inline unsigned pkbf(float a, float b) {
  __hip_bfloat162 h2 = __float22bfloat162_rn(float2{a, b});
  union { __hip_bfloat162 h; unsigned u; } cv;
  cv.h = h2;
  return cv.u;
}
__device__ inline float lo16f(unsigned u) { return __uint_as_float(u << 16); }
__device__ inline float hi16f(unsigned u) { return __uint_as_float(u & 0xffff0000u); }
__device__ inline float fast_tanh(float x) {
  float e = __expf(2.f * x);                 // inf ok -> 1
  float r = __builtin_amdgcn_rcpf(e + 1.f);
  return __builtin_fmaf(-2.f, r, 1.f);
}
__device__ inline unsigned enc_f(float f) {
  unsigned u = __float_as_uint(f);
  return (u & 0x80000000u) ? ~u : (u | 0x80000000u);
}
__device__ inline float dec_f(unsigned key) {
  unsigned bits = (key & 0x80000000u) ? (key ^ 0x80000000u) : ~key;
  return __uint_as_float(bits);
}
__device__ inline void sync_lds() {
  asm volatile("s_waitcnt lgkmcnt(0)\n\ts_barrier" ::: "memory");
}

// ---------------------------------------------------------------------------
// prep: transpose + bf16-cast weights. WfT/WbT:[256][128] WcT:[128][640]
// UfT/UbT:[256][256] (all [n][k]). Coalesced reads, strided writes (stores
// are fire-and-forget; strided loads would serialize 64 transactions/wave).
// ---------------------------------------------------------------------------
__global__ __launch_bounds__(256) void prep_kernel(
    const float* __restrict__ Wf, const float* __restrict__ Wb,
    const float* __restrict__ Wc, const float* __restrict__ Uf,
    const float* __restrict__ Ub,
    unsigned short* __restrict__ WfT, unsigned short* __restrict__ WbT,
    unsigned short* __restrict__ WcT, unsigned short* __restrict__ UfT,
    unsigned short* __restrict__ UbT) {
  int gid = blockIdx.x * 256 + threadIdx.x;
  int stride = gridDim.x * 256;
  for (int i = gid; i < 128 * 256; i += stride) {  // Wf/Wb [128][256]
    int k = i >> 8, n = i & 255;
    WfT[n * 128 + k] = f2bf(Wf[i]);
    WbT[n * 128 + k] = f2bf(Wb[i]);
  }
  for (int i = gid; i < 640 * 128; i += stride) {  // Wc [640][128]
    int k = i >> 7, n = i & 127;
    WcT[n * 640 + k] = f2bf(Wc[i]);
  }
  for (int i = gid; i < 256 * 256; i += stride) {  // Uf/Ub [256][256]
    int k = i >> 8, n = i & 255;
    UfT[n * 256 + k] = f2bf(Uf[i]);
    UbT[n * 256 + k] = f2bf(Ub[i]);
  }
}

// ---------------------------------------------------------------------------
// embxw: dirs 0/1: xw^T = W^T . e^T + b, packed units into x.
//        dir 2: plain gather of e_cur into q-half-split units [256,384).
// grid (128 tquads, 16 btiles, 3), 256 thr.
// ---------------------------------------------------------------------------
__global__ __launch_bounds__(256) void embxw_kernel(
    const int* __restrict__ idxL, const int* __restrict__ idxR,
    const int* __restrict__ idxC, const float* __restrict__ emb,
    const unsigned short* __restrict__ WfT, const unsigned short* __restrict__ WbT,
    const float* __restrict__ bfv, const float* __restrict__ bbv,
    unsigned short* __restrict__ x) {
  const int dir = blockIdx.z;
  const int t0 = blockIdx.x * 4;
  const int b0 = blockIdx.y * 16;
  const int tid = threadIdx.x;
  const int w = tid >> 6, lane = tid & 63, q = lane >> 4, l15 = lane & 15;

  if (dir == 2) {  // e_cur gather
    const int t = t0 + w;
    const int er = idxC[(b0 + l15) * T_ + t];
    const float* ep = emb + (size_t)er * E_;
#pragma unroll
    for (int u = 0; u < 8; ++u) {
      float4v a = *(const float4v*)(ep + 16 * u + 4 * q);
      uint2v pk = {pkbf(a[0], a[1]), pkbf(a[2], a[3])};
      int row = b0 + u + 8 * (q >> 1);
      *(uint2v*)(x + ((size_t)row * T_ + t) * 640 + 256 + 64 * (q & 1) +
                 4 * l15) = pk;
    }
    return;
  }

  const int* __restrict__ idx = dir ? idxR : idxL;
  const unsigned short* __restrict__ WT = dir ? WbT : WfT;
  const float* __restrict__ bias = dir ? bbv : bfv;

  short8 wfr[4][4];
#pragma unroll
  for (int mt = 0; mt < 4; ++mt)
#pragma unroll
    for (int kt = 0; kt < 4; ++kt)
      wfr[mt][kt] = *(const short8*)(WT + (64 * w + 16 * mt + l15) * 128 +
                                     kt * 32 + q * 8);
  float4v bv[4];
#pragma unroll
  for (int mt = 0; mt < 4; ++mt)
    bv[mt] = *(const float4v*)(bias + 64 * w + 16 * mt + 4 * q);

#pragma unroll 1
  for (int j = 0; j < 4; ++j) {
    const int t = t0 + j;
    const int er = idx[(b0 + l15) * T_ + t];
    const float* ep = emb + (size_t)er * E_;
    short8 efr[4];
#pragma unroll
    for (int kt = 0; kt < 4; ++kt) {
      const float* p8 = ep + kt * 32 + q * 8;
      float4v a0 = *(const float4v*)p8;
      float4v a1 = *(const float4v*)(p8 + 4);
      union { unsigned u[4]; short8 s; } cv;
      cv.u[0] = pkbf(a0[0], a0[1]);
      cv.u[1] = pkbf(a0[2], a0[3]);
      cv.u[2] = pkbf(a1[0], a1[1]);
      cv.u[3] = pkbf(a1[2], a1[3]);
      efr[kt] = cv.s;
    }
    float4v acc[4];
#pragma unroll
    for (int mt = 0; mt < 4; ++mt) acc[mt] = (float4v){0.f, 0.f, 0.f, 0.f};
#pragma unroll
    for (int kt = 0; kt < 4; ++kt)
#pragma unroll
      for (int mt = 0; mt < 4; ++mt)
        acc[mt] = __builtin_amdgcn_mfma_f32_16x16x32_bf16(wfr[mt][kt], efr[kt],
                                                          acc[mt], 0, 0, 0);
#pragma unroll
    for (int mt = 0; mt < 4; ++mt) {
      float4v v = acc[mt] + bv[mt];
      uint2v pk = {pkbf(v[0], v[1]), pkbf(v[2], v[3])};
      *(uint2v*)(x + ((size_t)(b0 + 4 * w + mt) * T_ + t) * 640 + dir * 384 +
                 lane * 4) = pk;
    }
  }
}

// ---------------------------------------------------------------------------
// rnn: h_t = tanh(U^T h^T ; C-seed = xw_t). One chain per block, 8 waves x
// 32 cols (2 same-chain waves/SIMD). 32 blocks. Unroll x2, prefetch 4.
// R4 configuration — measured 375 us (DS-volume floor of this decomposition).
// ---------------------------------------------------------------------------
__global__ __launch_bounds__(512, 2) void rnn_kernel(
    unsigned short* x, const unsigned short* __restrict__ UfT,
    const unsigned short* __restrict__ UbT) {
  const int dir = blockIdx.x & 1;
  const int b0 = (blockIdx.x >> 1) * 16;
  const unsigned short* __restrict__ UT = dir ? UbT : UfT;
  const int xoff = dir ? 384 : 0;
  const int tstep = dir ? -1 : 1;
  const int t0 = dir ? (T_ - 1) : 0;
  const ptrdiff_t dstep = (ptrdiff_t)tstep * 640;  // shorts per t-step

  const int tid = threadIdx.x;
  const int wv = tid >> 6, lane = tid & 63, q = lane >> 4, l15 = lane & 15;

  // stride 280 shorts: b128 bank-start 4*(3*l15+q)%32 -> 2-way (free)
  __shared__ __attribute__((aligned(16))) unsigned short hbuf[2][16][280];
  unsigned short* hb0 = &hbuf[0][0][0];
  unsigned short* hb1 = &hbuf[1][0][0];

  for (int i = tid; i < 16 * 280; i += 512) hb0[i] = 0;

  // U^T A-fragments for this wave's 32 output cols
  short8 ufr[2][8];
#pragma unroll
  for (int mt = 0; mt < 2; ++mt)
#pragma unroll
    for (int kt = 0; kt < 8; ++kt)
      ufr[mt][kt] = *(const short8*)(UT + (32 * wv + 16 * mt + l15) * H_ +
                                     kt * 32 + q * 8);

  // per-lane unit pointers: units u = 2*wv + mt
  unsigned short* ptrS[2];        // store slot (step t of current pair)
  const unsigned short* ptrL[2];  // load slot (t + 4*tstep)
  uint2v curA[2], curB[2], infA[2], infB[2];
#pragma unroll
  for (int mt = 0; mt < 2; ++mt) {
    unsigned short* base =
        x + (size_t)(b0 + 2 * wv + mt) * T_ * 640 + xoff + lane * 4;
    unsigned short* bt = base + (ptrdiff_t)t0 * 640;
    curA[mt] = *(const uint2v*)(bt);
    curB[mt] = *(const uint2v*)(bt + dstep);
    infA[mt] = *(const uint2v*)(bt + 2 * dstep);
    infB[mt] = *(const uint2v*)(bt + 3 * dstep);
    ptrS[mt] = bt;
    ptrL[mt] = bt + 4 * dstep;
  }

  const unsigned lrd = l15 * 280;            // LDS read row base (shorts)
  const unsigned lwr = l15 * 280 + 32 * wv;  // LDS write base (+16mt+4q)

  __syncthreads();

#pragma unroll 1
  for (int p = 0; p < 256; ++p) {
    // prefetch pair p+2's xw (steps 2p+4, 2p+5)
    uint2v ldA[2], ldB[2];
    if (p < 254) {
#pragma unroll
      for (int mt = 0; mt < 2; ++mt) {
        ldA[mt] = *(const uint2v*)(ptrL[mt]);
        ldB[mt] = *(const uint2v*)(ptrL[mt] + dstep);
      }
    } else {
#pragma unroll
      for (int mt = 0; mt < 2; ++mt) { ldA[mt] = infA[mt]; ldB[mt] = infB[mt]; }
    }
#pragma unroll
    for (int mt = 0; mt < 2; ++mt) ptrL[mt] += 2 * dstep;

    // ---- STEP A: read hb0, write hb1 ----
    {
      short8 afr[8];
#pragma unroll
      for (int kt = 0; kt < 8; ++kt)
        afr[kt] = *(const short8*)(hb0 + lrd + kt * 32 + q * 8);
      float4v acc[2];
#pragma unroll
      for (int mt = 0; mt < 2; ++mt)
        acc[mt] = (float4v){lo16f(curA[mt].x), hi16f(curA[mt].x),
                            lo16f(curA[mt].y), hi16f(curA[mt].y)};
#pragma unroll
      for (int kt = 0; kt < 8; ++kt)
#pragma unroll
        for (int mt = 0; mt < 2; ++mt)
          acc[mt] = __builtin_amdgcn_mfma_f32_16x16x32_bf16(
              ufr[mt][kt], afr[kt], acc[mt], 0, 0, 0);
#pragma unroll
      for (int mt = 0; mt < 2; ++mt) {
        uint2v hv = {pkbf(fast_tanh(acc[mt][0]), fast_tanh(acc[mt][1])),
                     pkbf(fast_tanh(acc[mt][2]), fast_tanh(acc[mt][3]))};
        *(uint2v*)(hb1 + lwr + 16 * mt + 4 * q) = hv;
        *(uint2v*)ptrS[mt] = hv;
      }
    }
    sync_lds();

    // ---- STEP B: read hb1, write hb0 ----
    {
      short8 afr[8];
#pragma unroll
      for (int kt = 0; kt < 8; ++kt)
        afr[kt] = *(const short8*)(hb1 + lrd + kt * 32 + q * 8);
      float4v acc[2];
#pragma unroll
      for (int mt = 0; mt < 2; ++mt)
        acc[mt] = (float4v){lo16f(curB[mt].x), hi16f(curB[mt].x),
                            lo16f(curB[mt].y), hi16f(curB[mt].y)};
#pragma unroll
      for (int kt = 0; kt < 8; ++kt)
#pragma unroll
        for (int mt = 0; mt < 2; ++mt)
          acc[mt] = __builtin_amdgcn_mfma_f32_16x16x32_bf16(
              ufr[mt][kt], afr[kt], acc[mt], 0, 0, 0);
#pragma unroll
      for (int mt = 0; mt < 2; ++mt) {
        uint2v hv = {pkbf(fast_tanh(acc[mt][0]), fast_tanh(acc[mt][1])),
                     pkbf(fast_tanh(acc[mt][2]), fast_tanh(acc[mt][3]))};
        *(uint2v*)(hb0 + lwr + 16 * mt + 4 * q) = hv;
        *(uint2v*)(ptrS[mt] + dstep) = hv;
      }
    }
#pragma unroll
    for (int mt = 0; mt < 2; ++mt) {
      ptrS[mt] += 2 * dstep;
      curA[mt] = infA[mt];
      curB[mt] = infB[mt];
      infA[mt] = ldA[mt];
      infB[mt] = ldB[mt];
    }
    sync_lds();
  }
}

// ---------------------------------------------------------------------------
// convpool: out = max_t tanh(x_row @ Wc + bc) = tanh(max_t(x_row @ Wc) + bc)
// (tanh monotonic -> bias+tanh deferred out of the t-loop: 128 tanh/wave -> 8)
// grid (16 btiles x 32 tchunks), 256 thr (4 waves x 32 c-cols). LDS dbuf.
// ---------------------------------------------------------------------------
__global__ __launch_bounds__(256, 2) void convpool_kernel(
    const unsigned short* __restrict__ x, const unsigned short* __restrict__ WcT,
    const float* __restrict__ bc, unsigned int* __restrict__ pooled) {
  const int b0 = (blockIdx.x & 15) * 16;
  const int t0 = (blockIdx.x >> 4) * 16;
  const int tid = threadIdx.x;
  const int w = tid >> 6, lane = tid & 63, q = lane >> 4, l15 = lane & 15;

  __shared__ __attribute__((aligned(16))) unsigned short tile[2][16][648];

  short8 wfr[2][20];
#pragma unroll
  for (int ct = 0; ct < 2; ++ct)
#pragma unroll
    for (int kt = 0; kt < 20; ++kt)
      wfr[ct][kt] = *(const short8*)(WcT +
                                     (size_t)(32 * w + 16 * ct + l15) * 640 +
                                     kt * 32 + q * 8);
  float4v bv[2];
#pragma unroll
  for (int ct = 0; ct < 2; ++ct)
    bv[ct] = *(const float4v*)(bc + 32 * w + 16 * ct + 4 * q);

  float4v mx[2];
  mx[0] = (float4v){-1e30f, -1e30f, -1e30f, -1e30f};
  mx[1] = mx[0];

  const int srow = tid >> 4, ssub = tid & 15;
  {
    const unsigned short* src = x + ((size_t)(b0 + srow) * T_ + t0) * 640;
#pragma unroll
    for (int j = 0; j < 5; ++j)
      *(short8*)&tile[0][srow][ssub * 8 + j * 128] =
          *(const short8*)(src + ssub * 8 + j * 128);
  }
  __syncthreads();

#pragma unroll 1
  for (int j = 0; j < 16; ++j) {
    const int t = t0 + j;
    const int buf = j & 1;
    if (j < 15) {
      const unsigned short* src = x + ((size_t)(b0 + srow) * T_ + t + 1) * 640;
#pragma unroll
      for (int jj = 0; jj < 5; ++jj)
        *(short8*)&tile[buf ^ 1][srow][ssub * 8 + jj * 128] =
            *(const short8*)(src + ssub * 8 + jj * 128);
    }
    float4v acc[2];
    acc[0] = (float4v){0.f, 0.f, 0.f, 0.f};
    acc[1] = (float4v){0.f, 0.f, 0.f, 0.f};
#pragma unroll
    for (int kt = 0; kt < 20; ++kt) {
      int row, so1, so2;
      if (kt < 8) {
        row = 2 * kt + (q >> 1);
        so1 = 64 * (2 * (q & 1)) + 4 * l15;
        so2 = so1 + 64;
      } else if (kt < 12) {
        row = 2 * (kt - 8) + (q >> 1) + 8 * (q & 1);
        so1 = 256 + 4 * l15;
        so2 = 320 + 4 * l15;
      } else {
        row = 2 * (kt - 12) + (q >> 1);
        so1 = 384 + 64 * (2 * (q & 1)) + 4 * l15;
        so2 = so1 + 64;
      }
      union { unsigned u[4]; short8 s; } cv;
      uint2v c1 = *(const uint2v*)&tile[buf][row][so1];
      uint2v c2 = *(const uint2v*)&tile[buf][row][so2];
      cv.u[0] = c1.x; cv.u[1] = c1.y; cv.u[2] = c2.x; cv.u[3] = c2.y;
      acc[0] = __builtin_amdgcn_mfma_f32_16x16x32_bf16(wfr[0][kt], cv.s,
                                                       acc[0], 0, 0, 0);
      acc[1] = __builtin_amdgcn_mfma_f32_16x16x32_bf16(wfr[1][kt], cv.s,
                                                       acc[1], 0, 0, 0);
    }
#pragma unroll
    for (int ct = 0; ct < 2; ++ct)
#pragma unroll
      for (int i = 0; i < 4; ++i)
        mx[ct][i] = fmaxf(mx[ct][i], acc[ct][i]);  // pre-activation max
    __syncthreads();
  }
#pragma unroll
  for (int ct = 0; ct < 2; ++ct)
#pragma unroll
    for (int i = 0; i < 4; ++i)
      atomicMax(pooled + (b0 + l15) * C_ + 32 * w + 16 * ct + 4 * q + i,
                enc_f(fast_tanh(mx[ct][i] + bv[ct][i])));
}

// ---------------------------------------------------------------------------
// dense: out = sigmoid(pooled @ Wd + bd)  [256,128]@[128,2]
// ---------------------------------------------------------------------------
__global__ __launch_bounds__(256) void dense_kernel(
    const unsigned int* __restrict__ pooled, const float* __restrict__ Wd,
    const float* __restrict__ bd, float* __restrict__ out) {
  int b = threadIdx.x;
  float s0 = bd[0], s1 = bd[1];
#pragma unroll 4
  for (int c = 0; c < C_; ++c) {
    float f = dec_f(pooled[b * C_ + c]);
    s0 += f * Wd[c * 2 + 0];
    s1 += f * Wd[c * 2 + 1];
  }
  out[b * 2 + 0] = 1.f / (1.f + __expf(-s0));
  out[b * 2 + 1] = 1.f / (1.f + __expf(-s1));
}

// ---------------------------------------------------------------------------
extern "C" void kernel_launch(void* const* d_in, const int* in_sizes, int n_in,
                              void* d_out, int out_size, void* d_ws, size_t ws_size,
                              hipStream_t stream) {
  const int* idxC = (const int*)d_in[0];
  const int* idxL = (const int*)d_in[1];
  const int* idxR = (const int*)d_in[2];
  const float* emb = (const float*)d_in[3];
  const float* Wf = (const float*)d_in[4];
  const float* Uf = (const float*)d_in[5];
  const float* bf_ = (const float*)d_in[6];
  const float* Wb = (const float*)d_in[7];
  const float* Ub = (const float*)d_in[8];
  const float* bb_ = (const float*)d_in[9];
  const float* Wc = (const float*)d_in[10];
  const float* bc = (const float*)d_in[11];
  const float* Wd = (const float*)d_in[12];
  const float* bd = (const float*)d_in[13];

  char* ws = (char*)d_ws;
  unsigned short* x = (unsigned short*)ws;                          // 167,772,160 B
  unsigned int* pooled = (unsigned int*)(ws + 167772160);           // 131,072 B
  unsigned short* WfT = (unsigned short*)(ws + 167772160 + 131072);
  unsigned short* WbT = WfT + 256 * 128;
  unsigned short* WcT = WbT + 256 * 128;
  unsigned short* UfT = WcT + 128 * 640;
  unsigned short* UbT = UfT + 256 * 256;

  hipMemsetAsync(pooled, 0, B_ * C_ * sizeof(unsigned int), stream);
  prep_kernel<<<64, 256, 0, stream>>>(Wf, Wb, Wc, Uf, Ub, WfT, WbT, WcT, UfT, UbT);
  embxw_kernel<<<dim3(128, 16, 3), 256, 0, stream>>>(idxL, idxR, idxC, emb,
                                                     WfT, WbT, bf_, bb_, x);
  rnn_kernel<<<32, 512, 0, stream>>>(x, UfT, UbT);
  convpool_kernel<<<512, 256, 0, stream>>>(x, WcT, bc, pooled);
  dense_kernel<<<1, 256, 0, stream>>>(pooled, Wd, bd, (float*)d_out);
}